// Round 6
// baseline (254.890 us; speedup 1.0000x reference)
//
#include <hip/hip_runtime.h>
#include <hip/hip_bf16.h>
#include <hip/hip_fp16.h>
#include <math.h>

// B=4, N=1024, C=512, H=8, D=64
// ws layout (bytes), total 24 MB:
//   qb  us  @ 0          (4,194,304)
//   kb  us  @ 4194304    (4,194,304)
//   vTb us  @ 8388608    (4,194,304)
//   apos f32@ 12582912   (1,048,576)
//   xh  us  @ 13631488   (4,194,304)  \ reused after qkv_mfma as
//   xl  us  @ 17825792   (4,194,304)  / outp1 f32 (8,388,608)
//   wTh us  @ 22020096   (1,572,864)  \ reused after qkv_mfma as
//   wTl us  @ 23592960   (1,572,864)  / ml0,ml1 f32 (262,144 each)
// d_out doubles as outp0 (unnormalized half-0 attention output).
//
// R5 -> R6: attn 3 blocks/CU (bias tile f16, 52.8 KB LDS), exp2 domain
// (log2e folded into q-scale and w2/b2), f32 softmax denominator,
// prep-kernel fusion (6 -> 4 launches).

typedef __attribute__((ext_vector_type(8))) short bh8;   // 8 bf16 in 4 VGPRs
typedef __attribute__((ext_vector_type(4))) float f32x4;

#define LOG2E 1.44269504f

static __device__ __forceinline__ ushort f2bf(float x) {
    __hip_bfloat16 h = __float2bfloat16(x);
    return *reinterpret_cast<ushort*>(&h);
}
static __device__ __forceinline__ float bf2f(ushort u) {
    unsigned v = ((unsigned)u) << 16;
    return __builtin_bit_cast(float, v);
}
static __device__ __forceinline__ ushort f2h(float x) {
    __half h = __float2half(x);
    return *reinterpret_cast<ushort*>(&h);
}
static __device__ __forceinline__ float h2f(ushort u) {
    __half h = __builtin_bit_cast(__half, u);
    return __half2float(h);
}

// ---------------- kernel 0: fused prep (pos_w1 | cast_x | cast_wT) ----------
// grid: [0,2048) cast_x, [2048,3072) pos_w1, [3072,3264) cast_wT
__global__ __launch_bounds__(256) void prep_kernel(
    const float* __restrict__ x, const float* __restrict__ pos,
    const float* __restrict__ w1, const float* __restrict__ wqkv,
    ushort* __restrict__ xh, ushort* __restrict__ xl,
    ushort* __restrict__ wTh, ushort* __restrict__ wTl,
    float* __restrict__ apos)
{
    __shared__ float t[64][65];
    const int bid = blockIdx.x;
    const int tid = threadIdx.x;

    if (bid < 2048) {
        // ---- cast_x: split x -> xh + xl (bf16 pair) ----
        const int idx = bid * 256 + tid;              // < 524288
        const float4 v = *(const float4*)&x[(size_t)idx * 4];
        ushort h0 = f2bf(v.x), h1 = f2bf(v.y), h2 = f2bf(v.z), h3 = f2bf(v.w);
        ushort l0 = f2bf(v.x - bf2f(h0)), l1 = f2bf(v.y - bf2f(h1));
        ushort l2 = f2bf(v.z - bf2f(h2)), l3 = f2bf(v.w - bf2f(h3));
        uint2 hu, lu;
        hu.x = (unsigned)h0 | ((unsigned)h1 << 16);
        hu.y = (unsigned)h2 | ((unsigned)h3 << 16);
        lu.x = (unsigned)l0 | ((unsigned)l1 << 16);
        lu.y = (unsigned)l2 | ((unsigned)l3 << 16);
        *(uint2*)&xh[(size_t)idx * 4] = hu;
        *(uint2*)&xl[(size_t)idx * 4] = lu;
    } else if (bid < 3072) {
        // ---- pos_w1: apos = pos @ w1 ----
        const int idx = (bid - 2048) * 256 + tid;     // < 262144
        const int bn = idx >> 6, j = idx & 63;
        const float px = pos[bn * 3 + 0];
        const float py = pos[bn * 3 + 1];
        const float pz = pos[bn * 3 + 2];
        apos[idx] = fmaf(px, w1[j], fmaf(py, w1[64 + j], pz * w1[128 + j]));
    } else {
        // ---- cast_wT: transpose + hi/lo split ----
        const int tb = bid - 3072;                    // 0..191
        const int n0 = (tb % 24) * 64;
        const int k0 = (tb / 24) * 64;
        const int c = tid & 63, r4 = tid >> 6;
#pragma unroll
        for (int i = 0; i < 16; ++i) {
            const int r = i * 4 + r4;                 // k-local
            t[r][c] = wqkv[(size_t)(k0 + r) * 1536 + n0 + c];
        }
        __syncthreads();
#pragma unroll
        for (int i = 0; i < 16; ++i) {
            const int r = i * 4 + r4;                 // n-local
            const float v = t[c][r];
            const ushort hv = f2bf(v);
            wTh[(size_t)(n0 + r) * 512 + k0 + c] = hv;
            wTl[(size_t)(n0 + r) * 512 + k0 + c] = f2bf(v - bf2f(hv));
        }
    }
}

// ---------------- kernel 1: qkv GEMM via split-bf16 MFMA ---------------------
// C = xh*wh + xh*wl + xl*wh (fp32 acc) + bias; q scaled by 0.125*log2e.
__global__ __launch_bounds__(256, 2) void qkv_mfma(
    const ushort* __restrict__ xh, const ushort* __restrict__ xl,
    const ushort* __restrict__ wTh, const ushort* __restrict__ wTl,
    const float* __restrict__ bqkv,
    ushort* __restrict__ qb, ushort* __restrict__ kb, ushort* __restrict__ vTb)
{
    __shared__ ushort Ah[128 * 68], Al[128 * 68], Bh[128 * 68], Bl[128 * 68];
    const int tid = threadIdx.x;
    const int m0 = blockIdx.x * 128;
    const int n0 = blockIdx.y * 128;
    const int wid = tid >> 6, lane = tid & 63;
    const int wr = wid >> 1, wc = wid & 1;
    const int lq = lane & 15, g = lane >> 4;

    f32x4 acc[4][4];
#pragma unroll
    for (int m = 0; m < 4; ++m)
#pragma unroll
        for (int n = 0; n < 4; ++n) acc[m][n] = (f32x4){0.f, 0.f, 0.f, 0.f};

    const int srow = tid >> 3;
    const int sc8 = (tid & 7) * 8;

    for (int kt = 0; kt < 8; ++kt) {
        const int kk0 = kt * 64;
        __syncthreads();
#pragma unroll
        for (int i = 0; i < 4; ++i) {
            const int row = i * 32 + srow;
            *(bh8*)&Ah[row * 68 + sc8] =
                *(const bh8*)&xh[(size_t)(m0 + row) * 512 + kk0 + sc8];
            *(bh8*)&Al[row * 68 + sc8] =
                *(const bh8*)&xl[(size_t)(m0 + row) * 512 + kk0 + sc8];
            *(bh8*)&Bh[row * 68 + sc8] =
                *(const bh8*)&wTh[(size_t)(n0 + row) * 512 + kk0 + sc8];
            *(bh8*)&Bl[row * 68 + sc8] =
                *(const bh8*)&wTl[(size_t)(n0 + row) * 512 + kk0 + sc8];
        }
        __syncthreads();
#pragma unroll
        for (int kc = 0; kc < 2; ++kc) {
            const int ko = kc * 32 + g * 8;
            bh8 afh[4], afl[4], bfh[4], bfl[4];
#pragma unroll
            for (int m = 0; m < 4; ++m) {
                afh[m] = *(const bh8*)&Ah[(wr * 64 + m * 16 + lq) * 68 + ko];
                afl[m] = *(const bh8*)&Al[(wr * 64 + m * 16 + lq) * 68 + ko];
            }
#pragma unroll
            for (int n = 0; n < 4; ++n) {
                bfh[n] = *(const bh8*)&Bh[(wc * 64 + n * 16 + lq) * 68 + ko];
                bfl[n] = *(const bh8*)&Bl[(wc * 64 + n * 16 + lq) * 68 + ko];
            }
#pragma unroll
            for (int m = 0; m < 4; ++m)
#pragma unroll
                for (int n = 0; n < 4; ++n) {
                    acc[m][n] = __builtin_amdgcn_mfma_f32_16x16x32_bf16(
                        afh[m], bfh[n], acc[m][n], 0, 0, 0);
                    acc[m][n] = __builtin_amdgcn_mfma_f32_16x16x32_bf16(
                        afh[m], bfl[n], acc[m][n], 0, 0, 0);
                    acc[m][n] = __builtin_amdgcn_mfma_f32_16x16x32_bf16(
                        afl[m], bfh[n], acc[m][n], 0, 0, 0);
                }
        }
    }

    // ---- epilogue: D col=lq (output col), row=g*4+r (x-row) ----
    const int s = n0 >> 9;              // 0:q 1:k 2:v (uniform per block)
    const int rowB = m0 + wr * 64;
    const int b = rowB >> 10;           // uniform
    const float QSCALE = 0.125f * LOG2E;
#pragma unroll
    for (int nt = 0; nt < 4; ++nt) {
        const int col = n0 + wc * 64 + nt * 16 + lq;
        const float bias_v = bqkv[col];
        const int h = (col >> 6) & 7, d = col & 63;
#pragma unroll
        for (int mt = 0; mt < 4; ++mt) {
            const int nloc = (rowB & 1023) + mt * 16 + g * 4;
            const float v0 = acc[mt][nt][0] + bias_v;
            const float v1 = acc[mt][nt][1] + bias_v;
            const float v2 = acc[mt][nt][2] + bias_v;
            const float v3 = acc[mt][nt][3] + bias_v;
            if (s == 0) {
                const size_t base = ((size_t)(b * 8 + h) * 1024 + nloc) * 64 + d;
                qb[base]       = f2bf(v0 * QSCALE);
                qb[base + 64]  = f2bf(v1 * QSCALE);
                qb[base + 128] = f2bf(v2 * QSCALE);
                qb[base + 192] = f2bf(v3 * QSCALE);
            } else if (s == 1) {
                const size_t base = ((size_t)(b * 8 + h) * 1024 + nloc) * 64 + d;
                kb[base]       = f2bf(v0);
                kb[base + 64]  = f2bf(v1);
                kb[base + 128] = f2bf(v2);
                kb[base + 192] = f2bf(v3);
            } else {
                uint2 u;
                u.x = (unsigned)f2bf(v0) | ((unsigned)f2bf(v1) << 16);
                u.y = (unsigned)f2bf(v2) | ((unsigned)f2bf(v3) << 16);
                *(uint2*)&vTb[((size_t)(b * 8 + h) * 64 + d) * 1024 + nloc] = u;
            }
        }
    }
}

// ---------------- kernel 2: fused bias-MLP + flash attention (key-split) -----
// 512 blocks = (batch, 16-query tile, key-half); 8 waves, wave w == head w.
// All softmax math in log2 domain (q pre-scaled by 0.125*log2e; bias*log2e).
__global__ __launch_bounds__(512, 6) void attn_fused(
    const ushort* __restrict__ qb, const ushort* __restrict__ kb,
    const ushort* __restrict__ vTb, const float* __restrict__ apos,
    const float* __restrict__ pos, const float* __restrict__ b1,
    const float* __restrict__ w2, const float* __restrict__ b2,
    float* __restrict__ outp0, float* __restrict__ outp1,
    float* __restrict__ ml0, float* __restrict__ ml1)
{
    const int bx = blockIdx.x;          // 0..511
    const int xcd = bx & 7;             // XCD swizzle: 2 XCDs per batch
    const int b = xcd >> 1;
    const int u = (bx >> 3) * 2 + (xcd & 1);  // 0..127
    const int nq0 = (u & 63) * 16;
    const int half = u >> 6;
    const int k0base = half * 512;

    float* __restrict__ outp = half ? outp1 : outp0;
    float* __restrict__ mlp  = half ? ml1 : ml0;

    const int tid = threadIdx.x;
    const int w = tid >> 6;             // wave id == head
    const int lane = tid & 63;
    const int lq = lane & 15;
    const int g = lane >> 4;

    // LDS: 16384 + 1024 + 17600 + 18432 + 576 = 54016 B -> 3 blocks/CU
    __shared__ __align__(16) float a_m_s[64][64];      // 16 KB
    __shared__ __align__(16) float pos_k_s[64][4];     // 1 KB
    __shared__ __align__(16) ushort bias_s[8 * 1100];  // 17.2 KB f16, head stride 1100, row 68
    __shared__ __align__(16) ushort p_lds[8][16][72];  // 18 KB bf16
    __shared__ float red_s[8][18];                     // 0.56 KB

    // ---- per-lane loop-invariant registers ----
    float a_n[16], b1r[16];
    {
        const float* anp = apos + (size_t)(b * 1024 + nq0 + lq) * 64;
        *(float4*)&a_n[0]  = *(const float4*)&anp[g * 8];
        *(float4*)&a_n[4]  = *(const float4*)&anp[g * 8 + 4];
        *(float4*)&a_n[8]  = *(const float4*)&anp[32 + g * 8];
        *(float4*)&a_n[12] = *(const float4*)&anp[32 + g * 8 + 4];
        *(float4*)&b1r[0]  = *(const float4*)&b1[g * 8];
        *(float4*)&b1r[4]  = *(const float4*)&b1[g * 8 + 4];
        *(float4*)&b1r[8]  = *(const float4*)&b1[32 + g * 8];
        *(float4*)&b1r[12] = *(const float4*)&b1[32 + g * 8 + 4];
    }
    const float px = pos[(size_t)(b * 1024 + nq0 + lq) * 3 + 0];
    const float py = pos[(size_t)(b * 1024 + nq0 + lq) * 3 + 1];
    const float pz = pos[(size_t)(b * 1024 + nq0 + lq) * 3 + 2];

    bh8 w2fa, w2fb;                     // w2 B-frags (pre-scaled by log2e)
#pragma unroll
    for (int e = 0; e < 8; ++e) {
        const int k0 = g * 8 + e, k1 = 32 + g * 8 + e;
        w2fa[e] = (short)((lq < 8) ? f2bf(w2[k0 * 8 + lq] * LOG2E) : 0);
        w2fb[e] = (short)((lq < 8) ? f2bf(w2[k1 * 8 + lq] * LOG2E) : 0);
    }
    const float b2r = (lq < 8) ? b2[lq] * LOG2E : 0.f;

    bh8 qf0, qf1;                       // Q B-frags (pre-scaled 0.125*log2e)
    {
        const ushort* qp = qb + ((size_t)(b * 8 + w) * 1024 + nq0 + lq) * 64;
        qf0 = *(const bh8*)&qp[g * 8];
        qf1 = *(const bh8*)&qp[32 + g * 8];
    }

    f32x4 o[4];
#pragma unroll
    for (int dt = 0; dt < 4; ++dt) o[dt] = (f32x4){0.f, 0.f, 0.f, 0.f};
    float m_run = -INFINITY, l_run = 0.f;

#define STAGE(m0v) do { \
        const float4* _src = (const float4*)(apos + (size_t)(b * 1024 + (m0v)) * 64); \
        float4* _dst = (float4*)&a_m_s[0][0]; \
        _dst[tid] = _src[tid]; \
        _dst[tid + 512] = _src[tid + 512]; \
        if (tid < 192) pos_k_s[tid / 3][tid % 3] = \
            pos[(size_t)(b * 1024 + (m0v) + tid / 3) * 3 + tid % 3]; \
    } while (0)

    STAGE(k0base);
    __syncthreads();

    for (int t16 = 0; t16 < 8; ++t16) {
        const int m0 = k0base + t16 * 64;

        // ---- bias MLP: wave w computes keys w*8..w*8+7, ALL heads, via MFMA ----
#pragma unroll
        for (int kk = 0; kk < 8; ++kk) {
            const int jl = w * 8 + kk;
            const float kx = pos_k_s[jl][0];
            const float ky = pos_k_s[jl][1];
            const float kz = pos_k_s[jl][2];
            const float dx = px - kx, dy = py - ky, dz = pz - kz;
            const float inv =
                1.f / (sqrtf(fmaf(dx, dx, fmaf(dy, dy, dz * dz))) + 1e-6f);
            const float* am = &a_m_s[jl][0];   // broadcast reads
            bh8 hf0, hf1;
#pragma unroll
            for (int e = 0; e < 8; ++e) {
                const float h0 =
                    fmaxf(fmaf(a_n[e] - am[g * 8 + e], inv, b1r[e]), 0.f);
                const float h1 =
                    fmaxf(fmaf(a_n[8 + e] - am[32 + g * 8 + e], inv, b1r[8 + e]), 0.f);
                hf0[e] = (short)f2bf(h0);
                hf1[e] = (short)f2bf(h1);
            }
            f32x4 acc = (f32x4){0.f, 0.f, 0.f, 0.f};
            acc = __builtin_amdgcn_mfma_f32_16x16x32_bf16(hf0, w2fa, acc, 0, 0, 0);
            acc = __builtin_amdgcn_mfma_f32_16x16x32_bf16(hf1, w2fb, acc, 0, 0, 0);
            if (lq < 8) {   // D: col=lq=head, row=g*4+r=query; store f16
#pragma unroll
                for (int r = 0; r < 4; ++r)
                    bias_s[lq * 1100 + (g * 4 + r) * 68 + jl] = f2h(acc[r] + b2r);
            }
        }
        __syncthreads();   // bias_s visible cross-wave; a_m reads done

        if (t16 < 7) STAGE(m0 + 64);   // single-buffer prefetch (safe: consumed
                                       // only after the tile-end barrier)

        // ---- S^T = mfma(K_tile, Q^T): D col=lq=query, row=g*4+r=key-local ----
        const ushort* kbp = kb + ((size_t)(b * 8 + w) * 1024 + m0) * 64;
        f32x4 s[4];
#pragma unroll
        for (int at = 0; at < 4; ++at) {
            const bh8 kf0 = *(const bh8*)&kbp[(at * 16 + lq) * 64 + g * 8];
            const bh8 kf1 = *(const bh8*)&kbp[(at * 16 + lq) * 64 + 32 + g * 8];
            f32x4 z = (f32x4){0.f, 0.f, 0.f, 0.f};
            z = __builtin_amdgcn_mfma_f32_16x16x32_bf16(kf0, qf0, z, 0, 0, 0);
            s[at] = __builtin_amdgcn_mfma_f32_16x16x32_bf16(kf1, qf1, z, 0, 0, 0);
        }

        // ---- online softmax in log2 domain (reduce over lanes ^16,^32) ----
        float sv[16];
        float pmax = -INFINITY;
#pragma unroll
        for (int at = 0; at < 4; ++at) {
            const int bb = w * 1100 + lq * 68 + at * 16 + g * 4;
            const uint2 bu = *(const uint2*)&bias_s[bb];
            sv[at * 4 + 0] = s[at][0] + h2f((ushort)(bu.x & 0xffff));
            sv[at * 4 + 1] = s[at][1] + h2f((ushort)(bu.x >> 16));
            sv[at * 4 + 2] = s[at][2] + h2f((ushort)(bu.y & 0xffff));
            sv[at * 4 + 3] = s[at][3] + h2f((ushort)(bu.y >> 16));
#pragma unroll
            for (int r = 0; r < 4; ++r) pmax = fmaxf(pmax, sv[at * 4 + r]);
        }
        pmax = fmaxf(pmax, __shfl_xor(pmax, 16));
        pmax = fmaxf(pmax, __shfl_xor(pmax, 32));
        const float mnew = fmaxf(m_run, pmax);
        const float alpha = exp2f(m_run - mnew);
        m_run = mnew;

        float rs = 0.f;
        ushort pb[16];
#pragma unroll
        for (int i = 0; i < 16; ++i) {
            const float p = exp2f(sv[i] - mnew);
            pb[i] = f2bf(p);
            rs += p;
        }
        rs += __shfl_xor(rs, 16);
        rs += __shfl_xor(rs, 32);
        l_run = l_run * alpha + rs;

#pragma unroll
        for (int at = 0; at < 4; ++at) {   // P -> wave-private LDS (no barrier)
            uint2 uv;
            uv.x = (unsigned)pb[at * 4 + 0] | ((unsigned)pb[at * 4 + 1] << 16);
            uv.y = (unsigned)pb[at * 4 + 2] | ((unsigned)pb[at * 4 + 3] << 16);
            *(uint2*)&p_lds[w][lq][at * 16 + g * 4] = uv;
        }
        red_s[w][lq] = alpha;

        float ar[4];
#pragma unroll
        for (int r = 0; r < 4; ++r) ar[r] = red_s[w][g * 4 + r];
#pragma unroll
        for (int dt = 0; dt < 4; ++dt) {
            o[dt][0] *= ar[0]; o[dt][1] *= ar[1];
            o[dt][2] *= ar[2]; o[dt][3] *= ar[3];
        }

        // ---- PV = mfma(P, V^T-frags): D col=lq=d-local, row=g*4+r=query ----
        const bh8 pa0 = *(const bh8*)&p_lds[w][lq][g * 8];
        const bh8 pa1 = *(const bh8*)&p_lds[w][lq][32 + g * 8];
        const ushort* vtp = vTb + ((size_t)(b * 8 + w) * 64) * 1024 + m0;
#pragma unroll
        for (int dt = 0; dt < 4; ++dt) {
            const bh8 vf0 = *(const bh8*)&vtp[(dt * 16 + lq) * 1024 + g * 8];
            const bh8 vf1 = *(const bh8*)&vtp[(dt * 16 + lq) * 1024 + 32 + g * 8];
            o[dt] = __builtin_amdgcn_mfma_f32_16x16x32_bf16(pa0, vf0, o[dt], 0, 0, 0);
            o[dt] = __builtin_amdgcn_mfma_f32_16x16x32_bf16(pa1, vf1, o[dt], 0, 0, 0);
        }
        __syncthreads();   // bias_s reads + a_m writes done before next tile
    }

    // ---- epilogue: unnormalized o + (m,l) per query (m in log2 domain) ----
    if (g == 0) {
        float2 mlv;
        mlv.x = m_run;
        mlv.y = l_run;
        *(float2*)&mlp[((size_t)(b * 8 + w) * 1024 + nq0 + lq) * 2] = mlv;
    }
#pragma unroll
    for (int dt = 0; dt < 4; ++dt)
#pragma unroll
        for (int r = 0; r < 4; ++r)
            outp[(size_t)(b * 1024 + nq0 + g * 4 + r) * 512 + w * 64 + dt * 16 + lq] =
                o[dt][r];
#undef STAGE
}

// ---------------- kernel 3: combine the two key-halves (log2-domain m) ------
__global__ __launch_bounds__(256) void combine_halves(
    const float* __restrict__ o0, const float* __restrict__ o1,
    const float* __restrict__ ml0, const float* __restrict__ ml1,
    float* __restrict__ outF)
{
    const int idx = blockIdx.x * 256 + threadIdx.x;   // < 524288
    const size_t c4 = (size_t)idx * 4;
    const int row = idx >> 7;            // b*1024+n
    const int coff = (idx & 127) * 4;
    const int h = coff >> 6;
    const int b = row >> 10, n = row & 1023;
    const size_t mli = ((size_t)(b * 8 + h) * 1024 + n) * 2;
    const float2 v0 = *(const float2*)&ml0[mli];
    const float2 v1 = *(const float2*)&ml1[mli];
    const float m = fmaxf(v0.x, v1.x);
    const float e0 = exp2f(v0.x - m), e1 = exp2f(v1.x - m);
    const float inv = 1.f / fmaf(v0.y, e0, v1.y * e1);
    const float4 a = *(const float4*)&o0[c4];
    const float4 bb = *(const float4*)&o1[c4];
    float4 r;
    r.x = fmaf(a.x, e0, bb.x * e1) * inv;
    r.y = fmaf(a.y, e0, bb.y * e1) * inv;
    r.z = fmaf(a.z, e0, bb.z * e1) * inv;
    r.w = fmaf(a.w, e0, bb.w * e1) * inv;
    *(float4*)&outF[c4] = r;
}

extern "C" void kernel_launch(void* const* d_in, const int* in_sizes, int n_in,
                              void* d_out, int out_size, void* d_ws, size_t ws_size,
                              hipStream_t stream) {
    const float* x    = (const float*)d_in[0];
    const float* pos  = (const float*)d_in[1];
    const float* wqkv = (const float*)d_in[2];
    const float* bqkv = (const float*)d_in[3];
    const float* w1   = (const float*)d_in[4];
    const float* b1   = (const float*)d_in[5];
    const float* w2   = (const float*)d_in[6];
    const float* b2   = (const float*)d_in[7];
    float* out = (float*)d_out;

    char* W = (char*)d_ws;
    ushort* qb    = (ushort*)W;
    ushort* kb    = (ushort*)(W + 4194304);
    ushort* vTb   = (ushort*)(W + 8388608);
    float*  apos  = (float*)(W + 12582912);
    ushort* xh    = (ushort*)(W + 13631488);
    ushort* xl    = (ushort*)(W + 17825792);
    float*  outp1 = (float*)(W + 13631488);   // aliases xh/xl (dead after qkv)
    ushort* wTh   = (ushort*)(W + 22020096);
    ushort* wTl   = (ushort*)(W + 23592960);
    float*  ml0   = (float*)(W + 22020096);   // aliases wTh (dead after qkv)
    float*  ml1   = (float*)(W + 22282240);
    float*  outp0 = out;                      // d_out as half-0 scratch

    hipLaunchKernelGGL(prep_kernel, dim3(3264), dim3(256), 0, stream,
                       x, pos, w1, wqkv, xh, xl, wTh, wTl, apos);
    hipLaunchKernelGGL(qkv_mfma, dim3(32, 12), dim3(256), 0, stream,
                       xh, xl, wTh, wTl, bqkv, qb, kb, vTb);
    hipLaunchKernelGGL(attn_fused, dim3(512), dim3(512), 0, stream,
                       qb, kb, vTb, apos, pos, b1, w2, b2,
                       outp0, outp1, ml0, ml1);
    hipLaunchKernelGGL(combine_halves, dim3(2048), dim3(256), 0, stream,
                       outp0, outp1, ml0, ml1, out);
}

// Round 7
// 203.252 us; speedup vs baseline: 1.2541x; 1.2541x over previous
//
#include <hip/hip_runtime.h>
#include <hip/hip_bf16.h>
#include <hip/hip_fp16.h>
#include <math.h>

// B=4, N=1024, C=512, H=8, D=64
// ws layout (bytes), total 24 MB:
//   qb  us  @ 0          (4,194,304)
//   kb  us  @ 4194304    (4,194,304)
//   vTb us  @ 8388608    (4,194,304)
//   apos f32@ 12582912   (1,048,576)
//   xh  us  @ 13631488   (4,194,304)  \ reused after qkv_mfma as
//   xl  us  @ 17825792   (4,194,304)  / outp1 f32 (8,388,608)
//   wTh us  @ 22020096   (1,572,864)  \ reused after qkv_mfma as
//   wTl us  @ 23592960   (1,572,864)  / ml0,ml1 f32 (262,144 each)
// d_out doubles as outp0 (unnormalized half-0 attention output).
//
// R6 -> R7: launch_bounds(512,6) -> (512,4). R6's 40-VGPR cap spilled the
// per-lane state to scratch (FETCH 219 MB, WRITE 238 MB). With the 54 KB LDS
// footprint, occupancy is LDS-limited at 3 blocks/CU; at the natural 64-VGPR
// allocation 6 waves/SIMD fit the register file, so no launch-bounds pressure
// is needed. // block=512, LDS 54272B: 3 blocks/CU, 64 VGPR -> no spill.

typedef __attribute__((ext_vector_type(8))) short bh8;   // 8 bf16 in 4 VGPRs
typedef __attribute__((ext_vector_type(4))) float f32x4;

#define LOG2E 1.44269504f

static __device__ __forceinline__ ushort f2bf(float x) {
    __hip_bfloat16 h = __float2bfloat16(x);
    return *reinterpret_cast<ushort*>(&h);
}
static __device__ __forceinline__ float bf2f(ushort u) {
    unsigned v = ((unsigned)u) << 16;
    return __builtin_bit_cast(float, v);
}
static __device__ __forceinline__ ushort f2h(float x) {
    __half h = __float2half(x);
    return *reinterpret_cast<ushort*>(&h);
}
static __device__ __forceinline__ float h2f(ushort u) {
    __half h = __builtin_bit_cast(__half, u);
    return __half2float(h);
}

// ---------------- kernel 0: fused prep (pos_w1 | cast_x | cast_wT) ----------
// grid: [0,2048) cast_x, [2048,3072) pos_w1, [3072,3264) cast_wT
__global__ __launch_bounds__(256) void prep_kernel(
    const float* __restrict__ x, const float* __restrict__ pos,
    const float* __restrict__ w1, const float* __restrict__ wqkv,
    ushort* __restrict__ xh, ushort* __restrict__ xl,
    ushort* __restrict__ wTh, ushort* __restrict__ wTl,
    float* __restrict__ apos)
{
    __shared__ float t[64][65];
    const int bid = blockIdx.x;
    const int tid = threadIdx.x;

    if (bid < 2048) {
        // ---- cast_x: split x -> xh + xl (bf16 pair) ----
        const int idx = bid * 256 + tid;              // < 524288
        const float4 v = *(const float4*)&x[(size_t)idx * 4];
        ushort h0 = f2bf(v.x), h1 = f2bf(v.y), h2 = f2bf(v.z), h3 = f2bf(v.w);
        ushort l0 = f2bf(v.x - bf2f(h0)), l1 = f2bf(v.y - bf2f(h1));
        ushort l2 = f2bf(v.z - bf2f(h2)), l3 = f2bf(v.w - bf2f(h3));
        uint2 hu, lu;
        hu.x = (unsigned)h0 | ((unsigned)h1 << 16);
        hu.y = (unsigned)h2 | ((unsigned)h3 << 16);
        lu.x = (unsigned)l0 | ((unsigned)l1 << 16);
        lu.y = (unsigned)l2 | ((unsigned)l3 << 16);
        *(uint2*)&xh[(size_t)idx * 4] = hu;
        *(uint2*)&xl[(size_t)idx * 4] = lu;
    } else if (bid < 3072) {
        // ---- pos_w1: apos = pos @ w1 ----
        const int idx = (bid - 2048) * 256 + tid;     // < 262144
        const int bn = idx >> 6, j = idx & 63;
        const float px = pos[bn * 3 + 0];
        const float py = pos[bn * 3 + 1];
        const float pz = pos[bn * 3 + 2];
        apos[idx] = fmaf(px, w1[j], fmaf(py, w1[64 + j], pz * w1[128 + j]));
    } else {
        // ---- cast_wT: transpose + hi/lo split ----
        const int tb = bid - 3072;                    // 0..191
        const int n0 = (tb % 24) * 64;
        const int k0 = (tb / 24) * 64;
        const int c = tid & 63, r4 = tid >> 6;
#pragma unroll
        for (int i = 0; i < 16; ++i) {
            const int r = i * 4 + r4;                 // k-local
            t[r][c] = wqkv[(size_t)(k0 + r) * 1536 + n0 + c];
        }
        __syncthreads();
#pragma unroll
        for (int i = 0; i < 16; ++i) {
            const int r = i * 4 + r4;                 // n-local
            const float v = t[c][r];
            const ushort hv = f2bf(v);
            wTh[(size_t)(n0 + r) * 512 + k0 + c] = hv;
            wTl[(size_t)(n0 + r) * 512 + k0 + c] = f2bf(v - bf2f(hv));
        }
    }
}

// ---------------- kernel 1: qkv GEMM via split-bf16 MFMA ---------------------
// C = xh*wh + xh*wl + xl*wh (fp32 acc) + bias; q scaled by 0.125*log2e.
__global__ __launch_bounds__(256, 2) void qkv_mfma(
    const ushort* __restrict__ xh, const ushort* __restrict__ xl,
    const ushort* __restrict__ wTh, const ushort* __restrict__ wTl,
    const float* __restrict__ bqkv,
    ushort* __restrict__ qb, ushort* __restrict__ kb, ushort* __restrict__ vTb)
{
    __shared__ ushort Ah[128 * 68], Al[128 * 68], Bh[128 * 68], Bl[128 * 68];
    const int tid = threadIdx.x;
    const int m0 = blockIdx.x * 128;
    const int n0 = blockIdx.y * 128;
    const int wid = tid >> 6, lane = tid & 63;
    const int wr = wid >> 1, wc = wid & 1;
    const int lq = lane & 15, g = lane >> 4;

    f32x4 acc[4][4];
#pragma unroll
    for (int m = 0; m < 4; ++m)
#pragma unroll
        for (int n = 0; n < 4; ++n) acc[m][n] = (f32x4){0.f, 0.f, 0.f, 0.f};

    const int srow = tid >> 3;
    const int sc8 = (tid & 7) * 8;

    for (int kt = 0; kt < 8; ++kt) {
        const int kk0 = kt * 64;
        __syncthreads();
#pragma unroll
        for (int i = 0; i < 4; ++i) {
            const int row = i * 32 + srow;
            *(bh8*)&Ah[row * 68 + sc8] =
                *(const bh8*)&xh[(size_t)(m0 + row) * 512 + kk0 + sc8];
            *(bh8*)&Al[row * 68 + sc8] =
                *(const bh8*)&xl[(size_t)(m0 + row) * 512 + kk0 + sc8];
            *(bh8*)&Bh[row * 68 + sc8] =
                *(const bh8*)&wTh[(size_t)(n0 + row) * 512 + kk0 + sc8];
            *(bh8*)&Bl[row * 68 + sc8] =
                *(const bh8*)&wTl[(size_t)(n0 + row) * 512 + kk0 + sc8];
        }
        __syncthreads();
#pragma unroll
        for (int kc = 0; kc < 2; ++kc) {
            const int ko = kc * 32 + g * 8;
            bh8 afh[4], afl[4], bfh[4], bfl[4];
#pragma unroll
            for (int m = 0; m < 4; ++m) {
                afh[m] = *(const bh8*)&Ah[(wr * 64 + m * 16 + lq) * 68 + ko];
                afl[m] = *(const bh8*)&Al[(wr * 64 + m * 16 + lq) * 68 + ko];
            }
#pragma unroll
            for (int n = 0; n < 4; ++n) {
                bfh[n] = *(const bh8*)&Bh[(wc * 64 + n * 16 + lq) * 68 + ko];
                bfl[n] = *(const bh8*)&Bl[(wc * 64 + n * 16 + lq) * 68 + ko];
            }
#pragma unroll
            for (int m = 0; m < 4; ++m)
#pragma unroll
                for (int n = 0; n < 4; ++n) {
                    acc[m][n] = __builtin_amdgcn_mfma_f32_16x16x32_bf16(
                        afh[m], bfh[n], acc[m][n], 0, 0, 0);
                    acc[m][n] = __builtin_amdgcn_mfma_f32_16x16x32_bf16(
                        afh[m], bfl[n], acc[m][n], 0, 0, 0);
                    acc[m][n] = __builtin_amdgcn_mfma_f32_16x16x32_bf16(
                        afl[m], bfh[n], acc[m][n], 0, 0, 0);
                }
        }
    }

    // ---- epilogue: D col=lq (output col), row=g*4+r (x-row) ----
    const int s = n0 >> 9;              // 0:q 1:k 2:v (uniform per block)
    const int rowB = m0 + wr * 64;
    const int b = rowB >> 10;           // uniform
    const float QSCALE = 0.125f * LOG2E;
#pragma unroll
    for (int nt = 0; nt < 4; ++nt) {
        const int col = n0 + wc * 64 + nt * 16 + lq;
        const float bias_v = bqkv[col];
        const int h = (col >> 6) & 7, d = col & 63;
#pragma unroll
        for (int mt = 0; mt < 4; ++mt) {
            const int nloc = (rowB & 1023) + mt * 16 + g * 4;
            const float v0 = acc[mt][nt][0] + bias_v;
            const float v1 = acc[mt][nt][1] + bias_v;
            const float v2 = acc[mt][nt][2] + bias_v;
            const float v3 = acc[mt][nt][3] + bias_v;
            if (s == 0) {
                const size_t base = ((size_t)(b * 8 + h) * 1024 + nloc) * 64 + d;
                qb[base]       = f2bf(v0 * QSCALE);
                qb[base + 64]  = f2bf(v1 * QSCALE);
                qb[base + 128] = f2bf(v2 * QSCALE);
                qb[base + 192] = f2bf(v3 * QSCALE);
            } else if (s == 1) {
                const size_t base = ((size_t)(b * 8 + h) * 1024 + nloc) * 64 + d;
                kb[base]       = f2bf(v0);
                kb[base + 64]  = f2bf(v1);
                kb[base + 128] = f2bf(v2);
                kb[base + 192] = f2bf(v3);
            } else {
                uint2 u;
                u.x = (unsigned)f2bf(v0) | ((unsigned)f2bf(v1) << 16);
                u.y = (unsigned)f2bf(v2) | ((unsigned)f2bf(v3) << 16);
                *(uint2*)&vTb[((size_t)(b * 8 + h) * 64 + d) * 1024 + nloc] = u;
            }
        }
    }
}

// ---------------- kernel 2: fused bias-MLP + flash attention (key-split) -----
// 512 blocks = (batch, 16-query tile, key-half); 8 waves, wave w == head w.
// All softmax math in log2 domain (q pre-scaled by 0.125*log2e; bias*log2e).
__global__ __launch_bounds__(512, 4) void attn_fused(
    const ushort* __restrict__ qb, const ushort* __restrict__ kb,
    const ushort* __restrict__ vTb, const float* __restrict__ apos,
    const float* __restrict__ pos, const float* __restrict__ b1,
    const float* __restrict__ w2, const float* __restrict__ b2,
    float* __restrict__ outp0, float* __restrict__ outp1,
    float* __restrict__ ml0, float* __restrict__ ml1)
{
    const int bx = blockIdx.x;          // 0..511
    const int xcd = bx & 7;             // XCD swizzle: 2 XCDs per batch
    const int b = xcd >> 1;
    const int u = (bx >> 3) * 2 + (xcd & 1);  // 0..127
    const int nq0 = (u & 63) * 16;
    const int half = u >> 6;
    const int k0base = half * 512;

    float* __restrict__ outp = half ? outp1 : outp0;
    float* __restrict__ mlp  = half ? ml1 : ml0;

    const int tid = threadIdx.x;
    const int w = tid >> 6;             // wave id == head
    const int lane = tid & 63;
    const int lq = lane & 15;
    const int g = lane >> 4;

    // LDS: 16384 + 1024 + 17600 + 18432 + 576 = 54016 B -> 3 blocks/CU
    __shared__ __align__(16) float a_m_s[64][64];      // 16 KB
    __shared__ __align__(16) float pos_k_s[64][4];     // 1 KB
    __shared__ __align__(16) ushort bias_s[8 * 1100];  // 17.2 KB f16, head stride 1100, row 68
    __shared__ __align__(16) ushort p_lds[8][16][72];  // 18 KB bf16
    __shared__ float red_s[8][18];                     // 0.56 KB

    // ---- per-lane loop-invariant registers ----
    float a_n[16], b1r[16];
    {
        const float* anp = apos + (size_t)(b * 1024 + nq0 + lq) * 64;
        *(float4*)&a_n[0]  = *(const float4*)&anp[g * 8];
        *(float4*)&a_n[4]  = *(const float4*)&anp[g * 8 + 4];
        *(float4*)&a_n[8]  = *(const float4*)&anp[32 + g * 8];
        *(float4*)&a_n[12] = *(const float4*)&anp[32 + g * 8 + 4];
        *(float4*)&b1r[0]  = *(const float4*)&b1[g * 8];
        *(float4*)&b1r[4]  = *(const float4*)&b1[g * 8 + 4];
        *(float4*)&b1r[8]  = *(const float4*)&b1[32 + g * 8];
        *(float4*)&b1r[12] = *(const float4*)&b1[32 + g * 8 + 4];
    }
    const float px = pos[(size_t)(b * 1024 + nq0 + lq) * 3 + 0];
    const float py = pos[(size_t)(b * 1024 + nq0 + lq) * 3 + 1];
    const float pz = pos[(size_t)(b * 1024 + nq0 + lq) * 3 + 2];

    bh8 w2fa, w2fb;                     // w2 B-frags (pre-scaled by log2e)
#pragma unroll
    for (int e = 0; e < 8; ++e) {
        const int k0 = g * 8 + e, k1 = 32 + g * 8 + e;
        w2fa[e] = (short)((lq < 8) ? f2bf(w2[k0 * 8 + lq] * LOG2E) : 0);
        w2fb[e] = (short)((lq < 8) ? f2bf(w2[k1 * 8 + lq] * LOG2E) : 0);
    }
    const float b2r = (lq < 8) ? b2[lq] * LOG2E : 0.f;

    bh8 qf0, qf1;                       // Q B-frags (pre-scaled 0.125*log2e)
    {
        const ushort* qp = qb + ((size_t)(b * 8 + w) * 1024 + nq0 + lq) * 64;
        qf0 = *(const bh8*)&qp[g * 8];
        qf1 = *(const bh8*)&qp[32 + g * 8];
    }

    f32x4 o[4];
#pragma unroll
    for (int dt = 0; dt < 4; ++dt) o[dt] = (f32x4){0.f, 0.f, 0.f, 0.f};
    float m_run = -INFINITY, l_run = 0.f;

#define STAGE(m0v) do { \
        const float4* _src = (const float4*)(apos + (size_t)(b * 1024 + (m0v)) * 64); \
        float4* _dst = (float4*)&a_m_s[0][0]; \
        _dst[tid] = _src[tid]; \
        _dst[tid + 512] = _src[tid + 512]; \
        if (tid < 192) pos_k_s[tid / 3][tid % 3] = \
            pos[(size_t)(b * 1024 + (m0v) + tid / 3) * 3 + tid % 3]; \
    } while (0)

    STAGE(k0base);
    __syncthreads();

    for (int t16 = 0; t16 < 8; ++t16) {
        const int m0 = k0base + t16 * 64;

        // ---- bias MLP: wave w computes keys w*8..w*8+7, ALL heads, via MFMA ----
#pragma unroll
        for (int kk = 0; kk < 8; ++kk) {
            const int jl = w * 8 + kk;
            const float kx = pos_k_s[jl][0];
            const float ky = pos_k_s[jl][1];
            const float kz = pos_k_s[jl][2];
            const float dx = px - kx, dy = py - ky, dz = pz - kz;
            const float inv =
                1.f / (sqrtf(fmaf(dx, dx, fmaf(dy, dy, dz * dz))) + 1e-6f);
            const float* am = &a_m_s[jl][0];   // broadcast reads
            bh8 hf0, hf1;
#pragma unroll
            for (int e = 0; e < 8; ++e) {
                const float h0 =
                    fmaxf(fmaf(a_n[e] - am[g * 8 + e], inv, b1r[e]), 0.f);
                const float h1 =
                    fmaxf(fmaf(a_n[8 + e] - am[32 + g * 8 + e], inv, b1r[8 + e]), 0.f);
                hf0[e] = (short)f2bf(h0);
                hf1[e] = (short)f2bf(h1);
            }
            f32x4 acc = (f32x4){0.f, 0.f, 0.f, 0.f};
            acc = __builtin_amdgcn_mfma_f32_16x16x32_bf16(hf0, w2fa, acc, 0, 0, 0);
            acc = __builtin_amdgcn_mfma_f32_16x16x32_bf16(hf1, w2fb, acc, 0, 0, 0);
            if (lq < 8) {   // D: col=lq=head, row=g*4+r=query; store f16
#pragma unroll
                for (int r = 0; r < 4; ++r)
                    bias_s[lq * 1100 + (g * 4 + r) * 68 + jl] = f2h(acc[r] + b2r);
            }
        }
        __syncthreads();   // bias_s visible cross-wave; a_m reads done

        if (t16 < 7) STAGE(m0 + 64);   // single-buffer prefetch (safe: consumed
                                       // only after the tile-end barrier)

        // ---- S^T = mfma(K_tile, Q^T): D col=lq=query, row=g*4+r=key-local ----
        const ushort* kbp = kb + ((size_t)(b * 8 + w) * 1024 + m0) * 64;
        f32x4 s[4];
#pragma unroll
        for (int at = 0; at < 4; ++at) {
            const bh8 kf0 = *(const bh8*)&kbp[(at * 16 + lq) * 64 + g * 8];
            const bh8 kf1 = *(const bh8*)&kbp[(at * 16 + lq) * 64 + 32 + g * 8];
            f32x4 z = (f32x4){0.f, 0.f, 0.f, 0.f};
            z = __builtin_amdgcn_mfma_f32_16x16x32_bf16(kf0, qf0, z, 0, 0, 0);
            s[at] = __builtin_amdgcn_mfma_f32_16x16x32_bf16(kf1, qf1, z, 0, 0, 0);
        }

        // ---- online softmax in log2 domain (reduce over lanes ^16,^32) ----
        float sv[16];
        float pmax = -INFINITY;
#pragma unroll
        for (int at = 0; at < 4; ++at) {
            const int bb = w * 1100 + lq * 68 + at * 16 + g * 4;
            const uint2 bu = *(const uint2*)&bias_s[bb];
            sv[at * 4 + 0] = s[at][0] + h2f((ushort)(bu.x & 0xffff));
            sv[at * 4 + 1] = s[at][1] + h2f((ushort)(bu.x >> 16));
            sv[at * 4 + 2] = s[at][2] + h2f((ushort)(bu.y & 0xffff));
            sv[at * 4 + 3] = s[at][3] + h2f((ushort)(bu.y >> 16));
#pragma unroll
            for (int r = 0; r < 4; ++r) pmax = fmaxf(pmax, sv[at * 4 + r]);
        }
        pmax = fmaxf(pmax, __shfl_xor(pmax, 16));
        pmax = fmaxf(pmax, __shfl_xor(pmax, 32));
        const float mnew = fmaxf(m_run, pmax);
        const float alpha = exp2f(m_run - mnew);
        m_run = mnew;

        float rs = 0.f;
        ushort pb[16];
#pragma unroll
        for (int i = 0; i < 16; ++i) {
            const float p = exp2f(sv[i] - mnew);
            pb[i] = f2bf(p);
            rs += p;
        }
        rs += __shfl_xor(rs, 16);
        rs += __shfl_xor(rs, 32);
        l_run = l_run * alpha + rs;

#pragma unroll
        for (int at = 0; at < 4; ++at) {   // P -> wave-private LDS (no barrier)
            uint2 uv;
            uv.x = (unsigned)pb[at * 4 + 0] | ((unsigned)pb[at * 4 + 1] << 16);
            uv.y = (unsigned)pb[at * 4 + 2] | ((unsigned)pb[at * 4 + 3] << 16);
            *(uint2*)&p_lds[w][lq][at * 16 + g * 4] = uv;
        }
        red_s[w][lq] = alpha;

        float ar[4];
#pragma unroll
        for (int r = 0; r < 4; ++r) ar[r] = red_s[w][g * 4 + r];
#pragma unroll
        for (int dt = 0; dt < 4; ++dt) {
            o[dt][0] *= ar[0]; o[dt][1] *= ar[1];
            o[dt][2] *= ar[2]; o[dt][3] *= ar[3];
        }

        // ---- PV = mfma(P, V^T-frags): D col=lq=d-local, row=g*4+r=query ----
        const bh8 pa0 = *(const bh8*)&p_lds[w][lq][g * 8];
        const bh8 pa1 = *(const bh8*)&p_lds[w][lq][32 + g * 8];
        const ushort* vtp = vTb + ((size_t)(b * 8 + w) * 64) * 1024 + m0;
#pragma unroll
        for (int dt = 0; dt < 4; ++dt) {
            const bh8 vf0 = *(const bh8*)&vtp[(dt * 16 + lq) * 1024 + g * 8];
            const bh8 vf1 = *(const bh8*)&vtp[(dt * 16 + lq) * 1024 + 32 + g * 8];
            o[dt] = __builtin_amdgcn_mfma_f32_16x16x32_bf16(pa0, vf0, o[dt], 0, 0, 0);
            o[dt] = __builtin_amdgcn_mfma_f32_16x16x32_bf16(pa1, vf1, o[dt], 0, 0, 0);
        }
        __syncthreads();   // bias_s reads + a_m writes done before next tile
    }

    // ---- epilogue: unnormalized o + (m,l) per query (m in log2 domain) ----
    if (g == 0) {
        float2 mlv;
        mlv.x = m_run;
        mlv.y = l_run;
        *(float2*)&mlp[((size_t)(b * 8 + w) * 1024 + nq0 + lq) * 2] = mlv;
    }
#pragma unroll
    for (int dt = 0; dt < 4; ++dt)
#pragma unroll
        for (int r = 0; r < 4; ++r)
            outp[(size_t)(b * 1024 + nq0 + g * 4 + r) * 512 + w * 64 + dt * 16 + lq] =
                o[dt][r];
#undef STAGE
}

// ---------------- kernel 3: combine the two key-halves (log2-domain m) ------
__global__ __launch_bounds__(256) void combine_halves(
    const float* __restrict__ o0, const float* __restrict__ o1,
    const float* __restrict__ ml0, const float* __restrict__ ml1,
    float* __restrict__ outF)
{
    const int idx = blockIdx.x * 256 + threadIdx.x;   // < 524288
    const size_t c4 = (size_t)idx * 4;
    const int row = idx >> 7;            // b*1024+n
    const int coff = (idx & 127) * 4;
    const int h = coff >> 6;
    const int b = row >> 10, n = row & 1023;
    const size_t mli = ((size_t)(b * 8 + h) * 1024 + n) * 2;
    const float2 v0 = *(const float2*)&ml0[mli];
    const float2 v1 = *(const float2*)&ml1[mli];
    const float m = fmaxf(v0.x, v1.x);
    const float e0 = exp2f(v0.x - m), e1 = exp2f(v1.x - m);
    const float inv = 1.f / fmaf(v0.y, e0, v1.y * e1);
    const float4 a = *(const float4*)&o0[c4];
    const float4 bb = *(const float4*)&o1[c4];
    float4 r;
    r.x = fmaf(a.x, e0, bb.x * e1) * inv;
    r.y = fmaf(a.y, e0, bb.y * e1) * inv;
    r.z = fmaf(a.z, e0, bb.z * e1) * inv;
    r.w = fmaf(a.w, e0, bb.w * e1) * inv;
    *(float4*)&outF[c4] = r;
}

extern "C" void kernel_launch(void* const* d_in, const int* in_sizes, int n_in,
                              void* d_out, int out_size, void* d_ws, size_t ws_size,
                              hipStream_t stream) {
    const float* x    = (const float*)d_in[0];
    const float* pos  = (const float*)d_in[1];
    const float* wqkv = (const float*)d_in[2];
    const float* bqkv = (const float*)d_in[3];
    const float* w1   = (const float*)d_in[4];
    const float* b1   = (const float*)d_in[5];
    const float* w2   = (const float*)d_in[6];
    const float* b2   = (const float*)d_in[7];
    float* out = (float*)d_out;

    char* W = (char*)d_ws;
    ushort* qb    = (ushort*)W;
    ushort* kb    = (ushort*)(W + 4194304);
    ushort* vTb   = (ushort*)(W + 8388608);
    float*  apos  = (float*)(W + 12582912);
    ushort* xh    = (ushort*)(W + 13631488);
    ushort* xl    = (ushort*)(W + 17825792);
    float*  outp1 = (float*)(W + 13631488);   // aliases xh/xl (dead after qkv)
    ushort* wTh   = (ushort*)(W + 22020096);
    ushort* wTl   = (ushort*)(W + 23592960);
    float*  ml0   = (float*)(W + 22020096);   // aliases wTh (dead after qkv)
    float*  ml1   = (float*)(W + 22282240);
    float*  outp0 = out;                      // d_out as half-0 scratch

    hipLaunchKernelGGL(prep_kernel, dim3(3264), dim3(256), 0, stream,
                       x, pos, w1, wqkv, xh, xl, wTh, wTl, apos);
    hipLaunchKernelGGL(qkv_mfma, dim3(32, 12), dim3(256), 0, stream,
                       xh, xl, wTh, wTl, bqkv, qb, kb, vTb);
    hipLaunchKernelGGL(attn_fused, dim3(512), dim3(512), 0, stream,
                       qb, kb, vTb, apos, pos, b1, w2, b2,
                       outp0, outp1, ml0, ml1);
    hipLaunchKernelGGL(combine_halves, dim3(2048), dim3(256), 0, stream,
                       outp0, outp1, ml0, ml1, out);
}